// Round 10
// baseline (479.183 us; speedup 1.0000x reference)
//
#include <hip/hip_runtime.h>

typedef unsigned int uint;
typedef unsigned short ushort;
typedef __attribute__((ext_vector_type(8))) short bf16x8;
typedef __attribute__((ext_vector_type(4))) float f32x4;
typedef __attribute__((ext_vector_type(4))) uint uintx4;

#define N_NODES 100000
#define N_EDGES 1600000
#define NB_C 256
#define TILE_C ((N_EDGES + NB_C - 1) / NB_C)
#define NB_D ((N_NODES + 511) / 512)
#define MG_GRID ((N_NODES + 63) / 64)
#define AGG_GRID 2048
constexpr float BN_EPS = 1e-5f;

__device__ __forceinline__ float bflo(uint w) { return __uint_as_float(w << 16); }
__device__ __forceinline__ float bfhi(uint w) { return __uint_as_float(w & 0xffff0000u); }
__device__ __forceinline__ ushort f2bf(float x) {
    uint u = __float_as_uint(x);
    uint r = (u + 0x7fffu + ((u >> 16) & 1u)) >> 16;
    return (ushort)r;
}
__device__ __forceinline__ uint pack2(float a, float b) {
    return (uint)f2bf(a) | ((uint)f2bf(b) << 16);
}

// per-wave int64 detection: all waves read the same 64 odd words -> consistent
__device__ __forceinline__ bool detect_i64(const int* __restrict__ ep)
{
    int lane = threadIdx.x & 63;
    unsigned long long nz = __ballot(ep[2 * lane + 1] != 0);
    return nz == 0ULL;
}

// ---------------- CSR build: atomic-free bucket sort ----------------
__global__ __launch_bounds__(256) void coarseA_kernel(const int* __restrict__ ep,
                                                      uint* __restrict__ ch)
{
    __shared__ uint lh[256];
    int t = threadIdx.x, blk = blockIdx.x;
    lh[t] = 0;
    bool i64 = detect_i64(ep);
    __syncthreads();
    int start = blk * TILE_C;
    int end = start + TILE_C;
    if (end > N_EDGES) end = N_EDGES;
    for (int e = start + t; e < end; e += 256) {
        int d = i64 ? ep[2 * (N_EDGES + e)] : ep[N_EDGES + e];
        atomicAdd(&lh[d >> 9], 1u);
    }
    __syncthreads();
    ch[t * NB_C + blk] = lh[t];
}

__global__ void scanB_kernel(uint* __restrict__ ch, uint* __restrict__ bucketBase)
{
    __shared__ uint tot[256];
    int t = threadIdx.x;
    uint s = 0;
    for (int i = 0; i < NB_C; i++) s += ch[t * NB_C + i];
    tot[t] = s;
    __syncthreads();
    for (int off = 1; off < 256; off <<= 1) {
        uint add = (t >= off) ? tot[t - off] : 0u;
        __syncthreads();
        tot[t] += add;
        __syncthreads();
    }
    uint base = tot[t] - s;
    bucketBase[t] = base;
    if (t == 255) bucketBase[256] = base + s;
    uint run = base;
    for (int i = 0; i < NB_C; i++) {
        uint c = ch[t * NB_C + i];
        ch[t * NB_C + i] = run;
        run += c;
    }
}

// pair packing: low 17 bits = src, bits 17..25 = dst & 511
__global__ __launch_bounds__(256) void scatterC_kernel(const int* __restrict__ ep,
                                                       const uint* __restrict__ ch,
                                                       uint* __restrict__ pair)
{
    __shared__ uint loff[256];
    int t = threadIdx.x, blk = blockIdx.x;
    loff[t] = ch[t * NB_C + blk];
    bool i64 = detect_i64(ep);
    __syncthreads();
    int start = blk * TILE_C;
    int end = start + TILE_C;
    if (end > N_EDGES) end = N_EDGES;
    for (int e = start + t; e < end; e += 256) {
        int s, d;
        if (i64) { s = ep[2 * e]; d = ep[2 * (N_EDGES + e)]; }
        else     { s = ep[e];     d = ep[N_EDGES + e]; }
        uint pos = atomicAdd(&loff[d >> 9], 1u);
        pair[pos] = (uint)s | ((uint)(d & 511) << 17);
    }
}

__global__ __launch_bounds__(256) void bucketD_kernel(const uint* __restrict__ pair,
                                                      const uint* __restrict__ bucketBase,
                                                      int* __restrict__ rowptr,
                                                      float* __restrict__ dinv,
                                                      int* __restrict__ colidx)
{
    __shared__ uint cnt[512], offp[512], s2[256];
    int bin = blockIdx.x, t = threadIdx.x;
    cnt[t] = 0; cnt[t + 256] = 0;
    __syncthreads();
    uint lo = bucketBase[bin], hi = bucketBase[bin + 1];
    for (uint p = lo + t; p < hi; p += 256)
        atomicAdd(&cnt[(pair[p] >> 17) & 511], 1u);
    __syncthreads();
    uint a = cnt[2 * t], b = cnt[2 * t + 1];
    s2[t] = a + b;
    __syncthreads();
    for (int off = 1; off < 256; off <<= 1) {
        uint add = (t >= off) ? s2[t - off] : 0u;
        __syncthreads();
        s2[t] += add;
        __syncthreads();
    }
    uint excl = s2[t] - (a + b);
    offp[2 * t] = excl;
    offp[2 * t + 1] = excl + a;
    __syncthreads();
    for (int k = t; k < 512; k += 256) {
        int d = bin * 512 + k;
        if (d < N_NODES) {
            rowptr[d] = (int)(lo + offp[k]);
            dinv[d] = rsqrtf((float)(cnt[k] + 1));
        }
    }
    if (bin == 0 && t == 0) rowptr[N_NODES] = N_EDGES;
    __syncthreads();
    for (uint p = lo + t; p < hi; p += 256) {
        uint pr = pair[p];
        uint pos = lo + atomicAdd(&offp[(pr >> 17) & 511], 1u);
        colidx[pos] = (int)(pr & 0x1FFFFu);
    }
}

// ---------------- xs[i][c] = bf16(dinv[i]*x[i][c]); dim 39 = dinv[i]; pad 40..63 = 0 ----------------
__global__ __launch_bounds__(256) void xscale_kernel(const float* __restrict__ x,
                                                     const float* __restrict__ dinv,
                                                     uint* __restrict__ xs)
{
    int idx = blockIdx.x * 256 + threadIdx.x;
    if (idx >= N_NODES * 32) return;
    int i = idx >> 5;
    int u = idx & 31;
    int c0 = 2 * u, c1 = 2 * u + 1;
    float di = dinv[i];
    float v0 = (c0 < 39) ? x[i * 39 + c0] * di : 0.f;
    float v1 = (c1 < 39) ? x[i * 39 + c1] * di : ((c1 == 39) ? di : 0.f);
    xs[idx] = pack2(v0, v1);
}

// ---------------- fused BN-fold + fragment pack ----------------
__global__ void foldpack_kernel(const float* __restrict__ W, const float* __restrict__ s,
                                const float* __restrict__ u, ushort* __restrict__ Wfrag,
                                float* __restrict__ vB, int din, int dout, int K)
{
    int CT = dout >> 4, KT = K >> 5;
    int nf = KT * CT;
    int b = blockIdx.x;
    if (b < nf) {
        int kt = b / CT, ct = b - kt * CT;
        for (int q = threadIdx.x; q < 512; q += 256) {
            int j = q & 7, lane = q >> 3;
            int k = kt * 32 + (lane >> 4) * 8 + j;
            int c = ct * 16 + (lane & 15);
            float v = 0.f;
            if (k < din) {
                float sv = s ? s[k] : 1.f;
                v = sv * W[k * dout + c];
            }
            Wfrag[(size_t)b * 512 + q] = f2bf(v);
        }
    } else {
        int c = threadIdx.x;
        if (u && c < dout) {
            float acc = 0.f;
            for (int k = 0; k < din; k++) acc += u[k] * W[k * dout + c];
            vB[c] = acc;
        }
    }
}

// ---------------- FUSED: agg (D=64) -> LDS tile -> MFMA GEMM ----------------
// Each block owns 64 nodes; wave w aggregates + consumes rows w*16..w*16+15 (no barrier).
// GMODE 0: t=relu(acc+bias); stats; out bf16 = dinv[r]*t       (layer 1)
// GMODE 1: t=relu(acc+bias+rowsumP[r]*vB); stats; out bf16 = t (layer 2)
template <int DOUT, int GMODE, int WRSUM>
__global__ __launch_bounds__(256) void fused_kernel(
    const ushort* __restrict__ table, const int* __restrict__ rowptr,
    const int* __restrict__ colidx, const float* __restrict__ dinv,
    const ushort* __restrict__ Wfrag, const float* __restrict__ bias,
    const float* __restrict__ vB, float* __restrict__ rowsumP,
    ushort* __restrict__ outB, float* __restrict__ Psum, float* __restrict__ Psq)
{
    constexpr int KT = 2, CT = DOUT / 16;
    __shared__ ushort atile[64 * 72];
    int tid = threadIdx.x, lane = tid & 63, wid = tid >> 6;
    int seg = lane & 7, slot = lane >> 3;
    const ushort* segbase = table + seg * 8;
    int r0 = blockIdx.x * 64;

    // ---- aggregation phase: one wave per node, 16 nodes per wave ----
    for (int t = 0; t < 16; ++t) {
        int row = wid * 16 + t;
        int i = r0 + row;
        float acc[8] = {};
        if (i < N_NODES) {
            int s0 = rowptr[i], e0 = rowptr[i + 1];
            if (slot == 0) {
                const uintx4 w = *(const uintx4*)(segbase + (size_t)i * 64);
                acc[0] = bflo(w.x); acc[1] = bfhi(w.x);
                acc[2] = bflo(w.y); acc[3] = bfhi(w.y);
                acc[4] = bflo(w.z); acc[5] = bfhi(w.z);
                acc[6] = bflo(w.w); acc[7] = bfhi(w.w);
            }
            for (int eb = s0; eb < e0; eb += 16) {
                int e1 = eb + slot, e2 = eb + 8 + slot;
                uintx4 w1 = {0u, 0u, 0u, 0u}, w2 = {0u, 0u, 0u, 0u};
                if (e1 < e0) w1 = *(const uintx4*)(segbase + (size_t)colidx[e1] * 64);
                if (e2 < e0) w2 = *(const uintx4*)(segbase + (size_t)colidx[e2] * 64);
                acc[0] += bflo(w1.x) + bflo(w2.x);
                acc[1] += bfhi(w1.x) + bfhi(w2.x);
                acc[2] += bflo(w1.y) + bflo(w2.y);
                acc[3] += bfhi(w1.y) + bfhi(w2.y);
                acc[4] += bflo(w1.z) + bflo(w2.z);
                acc[5] += bfhi(w1.z) + bfhi(w2.z);
                acc[6] += bflo(w1.w) + bflo(w2.w);
                acc[7] += bfhi(w1.w) + bfhi(w2.w);
            }
#pragma unroll
            for (int m = 8; m < 64; m <<= 1) {
#pragma unroll
                for (int v = 0; v < 8; v++) acc[v] += __shfl_xor(acc[v], m);
            }
        }
        if (slot == 0) {
            float di = (i < N_NODES) ? dinv[i] : 0.f;
            uintx4 pk;
            pk.x = pack2(di * acc[0], di * acc[1]);
            pk.y = pack2(di * acc[2], di * acc[3]);
            pk.z = pack2(di * acc[4], di * acc[5]);
            pk.w = pack2(di * acc[6], di * acc[7]);
            *(uintx4*)&atile[row * 72 + seg * 8] = pk;
            if constexpr (WRSUM) {
                if (seg == 4 && i < N_NODES) rowsumP[i] = di * acc[7]; // dim 39 carries dinv
            }
        }
    }

    // ---- GEMM phase: wave consumes its own LDS rows (no barrier needed) ----
    const ushort* aptr = &atile[(wid * 16 + (lane & 15)) * 72 + (lane >> 4) * 8];
    f32x4 gacc[CT];
#pragma unroll
    for (int ct = 0; ct < CT; ct++) gacc[ct] = (f32x4){0.f, 0.f, 0.f, 0.f};
#pragma unroll
    for (int kt = 0; kt < KT; kt++) {
        bf16x8 af = *(const bf16x8*)(aptr + kt * 32);
        const ushort* wp = Wfrag + ((size_t)(kt * CT) * 64 + lane) * 8;
#pragma unroll
        for (int ct = 0; ct < CT; ct++) {
            bf16x8 bfr = *(const bf16x8*)(wp + (size_t)ct * 64 * 8);
            gacc[ct] = __builtin_amdgcn_mfma_f32_16x16x32_bf16(af, bfr, gacc[ct], 0, 0, 0);
        }
    }

    int colbase = lane & 15;
    int rgrp = lane >> 4;
    int r0w = r0 + wid * 16;
    int rows[4]; bool rok[4];
    float rP[4], rD[4];
#pragma unroll
    for (int i = 0; i < 4; i++) {
        int r = r0w + rgrp * 4 + i;
        rows[i] = r;
        rok[i] = (r < N_NODES);
        int rc = rok[i] ? r : 0;
        if constexpr (GMODE == 1) rP[i] = rowsumP[rc];
        else rD[i] = dinv[rc];
    }

    __shared__ float ssum[DOUT], ssq[DOUT];
    for (int c = tid; c < DOUT; c += 256) { ssum[c] = 0.f; ssq[c] = 0.f; }
    __syncthreads();

#pragma unroll
    for (int ct = 0; ct < CT; ct++) {
        int col = ct * 16 + colbase;
        float b = bias[col];
        float b2 = 0.f;
        if constexpr (GMODE == 1) b2 = vB[col];
        float cs = 0.f, cq = 0.f;
#pragma unroll
        for (int i = 0; i < 4; i++) {
            float v = gacc[ct][i] + b;
            if constexpr (GMODE == 1) v = fmaf(rP[i], b2, v);
            v = fmaxf(v, 0.f);
            float w = (GMODE == 1) ? v : rD[i] * v;
            if (rok[i]) {
                outB[(size_t)rows[i] * DOUT + col] = f2bf(w);
                cs += v; cq += v * v;
            }
        }
        cs += __shfl_xor(cs, 16); cs += __shfl_xor(cs, 32);
        cq += __shfl_xor(cq, 16); cq += __shfl_xor(cq, 32);
        if (rgrp == 0) {
            atomicAdd(&ssum[col], cs);
            atomicAdd(&ssq[col], cq);
        }
    }
    __syncthreads();
    for (int c = tid; c < DOUT; c += 256) {
        Psum[(size_t)c * gridDim.x + blockIdx.x] = ssum[c];
        Psq[(size_t)c * gridDim.x + blockIdx.x] = ssq[c];
    }
}

// ---------------- aggregation: wide dwordx4 gathers, 2x unrolled (L3/L4) ----------------
// MODE 1: out bf16 = relu(dinv_i*acc + bias), stats partials
template <int D, int MODE, int WRSUM>
__global__ __launch_bounds__(256) void agg_kernel(
    const ushort* __restrict__ table, const int* __restrict__ rowptr,
    const int* __restrict__ colidx, const float* __restrict__ dinv,
    const float* __restrict__ bias,
    ushort* __restrict__ outB, float* __restrict__ rowsumP,
    float* __restrict__ Psum, float* __restrict__ Psq)
{
    constexpr int LPE = D / 8;
    constexpr int S = 64 / LPE;
    int tid = threadIdx.x;
    int lane = tid & 63, wid = tid >> 6;
    int seg = lane & (LPE - 1);
    int slot = lane / LPE;
    const ushort* segbase = table + seg * 8;

    float bv[8];
    if constexpr (MODE == 1) {
        float4 b0 = *(const float4*)&bias[seg * 8];
        float4 b1 = *(const float4*)&bias[seg * 8 + 4];
        bv[0] = b0.x; bv[1] = b0.y; bv[2] = b0.z; bv[3] = b0.w;
        bv[4] = b1.x; bv[5] = b1.y; bv[6] = b1.z; bv[7] = b1.w;
    }
    float lsum[8] = {}, lsq[8] = {};

    for (int i = blockIdx.x * 4 + wid; i < N_NODES; i += gridDim.x * 4) {
        int iu = __builtin_amdgcn_readfirstlane(i);
        int s0 = rowptr[iu], e0 = rowptr[iu + 1];
        float acc[8] = {};
        if (slot == 0) {
            const uintx4 w = *(const uintx4*)(segbase + (size_t)iu * D);
            acc[0] = bflo(w.x); acc[1] = bfhi(w.x);
            acc[2] = bflo(w.y); acc[3] = bfhi(w.y);
            acc[4] = bflo(w.z); acc[5] = bfhi(w.z);
            acc[6] = bflo(w.w); acc[7] = bfhi(w.w);
        }
        for (int eb = s0; eb < e0; eb += 2 * S) {
            int e1 = eb + slot, e2 = eb + S + slot;
            uintx4 w1 = {0u, 0u, 0u, 0u}, w2 = {0u, 0u, 0u, 0u};
            if (e1 < e0) w1 = *(const uintx4*)(segbase + (size_t)colidx[e1] * D);
            if (e2 < e0) w2 = *(const uintx4*)(segbase + (size_t)colidx[e2] * D);
            acc[0] += bflo(w1.x) + bflo(w2.x);
            acc[1] += bfhi(w1.x) + bfhi(w2.x);
            acc[2] += bflo(w1.y) + bflo(w2.y);
            acc[3] += bfhi(w1.y) + bfhi(w2.y);
            acc[4] += bflo(w1.z) + bflo(w2.z);
            acc[5] += bfhi(w1.z) + bfhi(w2.z);
            acc[6] += bflo(w1.w) + bflo(w2.w);
            acc[7] += bfhi(w1.w) + bfhi(w2.w);
        }
#pragma unroll
        for (int m = LPE; m < 64; m <<= 1) {
#pragma unroll
            for (int v = 0; v < 8; v++) acc[v] += __shfl_xor(acc[v], m);
        }
        if (slot == 0) {
            float di = dinv[iu];
            if constexpr (MODE == 0) {
                uintx4 pk;
                pk.x = pack2(di * acc[0], di * acc[1]);
                pk.y = pack2(di * acc[2], di * acc[3]);
                pk.z = pack2(di * acc[4], di * acc[5]);
                pk.w = pack2(di * acc[6], di * acc[7]);
                *(uintx4*)(outB + (size_t)iu * D + seg * 8) = pk;
                if constexpr (WRSUM) {
                    if (seg == 4) rowsumP[iu] = di * acc[7];
                }
            } else {
                float t[8];
#pragma unroll
                for (int v = 0; v < 8; v++) {
                    t[v] = fmaxf(fmaf(di, acc[v], bv[v]), 0.f);
                    lsum[v] += t[v];
                    lsq[v] += t[v] * t[v];
                }
                uintx4 pk;
                pk.x = pack2(t[0], t[1]); pk.y = pack2(t[2], t[3]);
                pk.z = pack2(t[4], t[5]); pk.w = pack2(t[6], t[7]);
                *(uintx4*)(outB + (size_t)iu * D + seg * 8) = pk;
            }
        }
    }

    if constexpr (MODE == 1) {
        __shared__ float ssum[D], ssq[D];
        for (int c = tid; c < D; c += 256) { ssum[c] = 0.f; ssq[c] = 0.f; }
        __syncthreads();
        if (slot == 0) {
#pragma unroll
            for (int v = 0; v < 8; v++) {
                atomicAdd(&ssum[seg * 8 + v], lsum[v]);
                atomicAdd(&ssq[seg * 8 + v], lsq[v]);
            }
        }
        __syncthreads();
        for (int c = tid; c < D; c += 256) {
            Psum[(size_t)c * gridDim.x + blockIdx.x] = ssum[c];
            Psq[(size_t)c * gridDim.x + blockIdx.x] = ssq[c];
        }
    }
}

// ---------------- MFMA GEMM (row-major A and out) ----------------
// MODE 2: z=acc+bias; out bf16 = dinv[r]*z
template <int K, int DOUT, int MODE>
__global__ __launch_bounds__(256) void mgemm_kernel(
    const ushort* __restrict__ A, const ushort* __restrict__ Wfrag,
    const float* __restrict__ bias, const float* __restrict__ bias2,
    const float* __restrict__ rowsumP, const float* __restrict__ dinv,
    ushort* __restrict__ outB, float* __restrict__ Psum, float* __restrict__ Psq)
{
    constexpr int KT = K / 32, CT = DOUT / 16;
    int tid = threadIdx.x;
    int lane = tid & 63, wid = tid >> 6;
    int r0 = blockIdx.x * 64 + wid * 16;
    int arow = r0 + (lane & 15);
    if (arow >= N_NODES) arow = N_NODES - 1;
    const ushort* aptr = A + (size_t)arow * K + (lane >> 4) * 8;

    f32x4 acc[CT];
#pragma unroll
    for (int ct = 0; ct < CT; ct++) acc[ct] = (f32x4){0.f, 0.f, 0.f, 0.f};

#pragma unroll
    for (int kt = 0; kt < KT; kt++) {
        bf16x8 af = *(const bf16x8*)(aptr + kt * 32);
        const ushort* wp = Wfrag + ((size_t)(kt * CT) * 64 + lane) * 8;
#pragma unroll
        for (int ct = 0; ct < CT; ct++) {
            bf16x8 bfr = *(const bf16x8*)(wp + (size_t)ct * 64 * 8);
            acc[ct] = __builtin_amdgcn_mfma_f32_16x16x32_bf16(af, bfr, acc[ct], 0, 0, 0);
        }
    }

    int colbase = lane & 15;
    int rgrp = lane >> 4;
    int rows[4]; bool rok[4];
    float rD[4];
#pragma unroll
    for (int i = 0; i < 4; i++) {
        int r = r0 + rgrp * 4 + i;
        rows[i] = r;
        rok[i] = (r < N_NODES);
        int rc = rok[i] ? r : 0;
        rD[i] = dinv[rc];
    }

#pragma unroll
    for (int ct = 0; ct < CT; ct++) {
        int col = ct * 16 + colbase;
        float b = bias[col];
#pragma unroll
        for (int i = 0; i < 4; i++) {
            float v = acc[ct][i] + b;
            float w = rD[i] * v;
            if (rok[i]) outB[(size_t)rows[i] * DOUT + col] = f2bf(w);
        }
    }
}

// ---------------- BN stat reduce -> scale/shift ----------------
__global__ __launch_bounds__(256) void reduce_bn_kernel(
    const float* __restrict__ Psum, const float* __restrict__ Psq, int nb,
    const float* __restrict__ g, const float* __restrict__ be,
    float* __restrict__ sOut, float* __restrict__ uOut)
{
    int c = blockIdx.x, t = threadIdx.x;
    float s = 0.f, q = 0.f;
    for (int i = t; i < nb; i += 256) {
        s += Psum[(size_t)c * nb + i];
        q += Psq[(size_t)c * nb + i];
    }
    __shared__ float rs[256], rq[256];
    rs[t] = s; rq[t] = q;
    __syncthreads();
    for (int off = 128; off > 0; off >>= 1) {
        if (t < off) { rs[t] += rs[t + off]; rq[t] += rq[t + off]; }
        __syncthreads();
    }
    if (t == 0) {
        float mu = rs[0] * (1.0f / N_NODES);
        float var = rq[0] * (1.0f / N_NODES) - mu * mu;
        float sv = g[c] * rsqrtf(var + BN_EPS);
        sOut[c] = sv;
        uOut[c] = be[c] - mu * sv;
    }
}

// ---------------- final: h4 = s4*t4+u4 (t4 [N,32] bf16), logits = h4@Wc+bc ----------------
__global__ __launch_bounds__(256) void final_kernel(
    const ushort* __restrict__ t4, const float* __restrict__ sArr,
    const float* __restrict__ uArr, const float* __restrict__ Wc,
    const float* __restrict__ bc, float* __restrict__ out_logits,
    float* __restrict__ out_h)
{
    __shared__ float sc[32], sh2[32], Wcs[160], bcs[5];
    int t = threadIdx.x;
    if (t < 32) { sc[t] = sArr[t]; sh2[t] = uArr[t]; }
    if (t < 160) Wcs[t] = Wc[t];
    if (t < 5) bcs[t] = bc[t];
    __syncthreads();
    int i = blockIdx.x * blockDim.x + t;
    if (i >= N_NODES) return;
    float hv[32];
    const uint* tp = (const uint*)(t4 + (size_t)i * 32);
#pragma unroll
    for (int q = 0; q < 4; q++) {
        uintx4 w = *(const uintx4*)(tp + q * 4);
        int f0 = q * 8;
        hv[f0 + 0] = fmaf(sc[f0 + 0], bflo(w.x), sh2[f0 + 0]);
        hv[f0 + 1] = fmaf(sc[f0 + 1], bfhi(w.x), sh2[f0 + 1]);
        hv[f0 + 2] = fmaf(sc[f0 + 2], bflo(w.y), sh2[f0 + 2]);
        hv[f0 + 3] = fmaf(sc[f0 + 3], bfhi(w.y), sh2[f0 + 3]);
        hv[f0 + 4] = fmaf(sc[f0 + 4], bflo(w.z), sh2[f0 + 4]);
        hv[f0 + 5] = fmaf(sc[f0 + 5], bfhi(w.z), sh2[f0 + 5]);
        hv[f0 + 6] = fmaf(sc[f0 + 6], bflo(w.w), sh2[f0 + 6]);
        hv[f0 + 7] = fmaf(sc[f0 + 7], bfhi(w.w), sh2[f0 + 7]);
    }
#pragma unroll
    for (int f0 = 0; f0 < 32; f0 += 4) {
        float4 v = {hv[f0], hv[f0 + 1], hv[f0 + 2], hv[f0 + 3]};
        *(float4*)&out_h[(size_t)i * 32 + f0] = v;
    }
    float o[5];
#pragma unroll
    for (int c = 0; c < 5; c++) o[c] = bcs[c];
#pragma unroll
    for (int f = 0; f < 32; f++) {
        float hvf = hv[f];
#pragma unroll
        for (int c = 0; c < 5; c++) o[c] = fmaf(hvf, Wcs[f * 5 + c], o[c]);
    }
#pragma unroll
    for (int c = 0; c < 5; c++) out_logits[(size_t)i * 5 + c] = o[c];
}

extern "C" void kernel_launch(void* const* d_in, const int* in_sizes, int n_in,
                              void* d_out, int out_size, void* d_ws, size_t ws_size,
                              hipStream_t stream)
{
    const float* x = (const float*)d_in[0];
    const int* ei = (const int*)d_in[1];
    const float* W1 = (const float*)d_in[2];
    const float* b1 = (const float*)d_in[3];
    const float* g1 = (const float*)d_in[4];
    const float* be1 = (const float*)d_in[5];
    const float* W2 = (const float*)d_in[6];
    const float* b2 = (const float*)d_in[7];
    const float* g2 = (const float*)d_in[8];
    const float* be2 = (const float*)d_in[9];
    const float* W3 = (const float*)d_in[10];
    const float* b3 = (const float*)d_in[11];
    const float* g3 = (const float*)d_in[12];
    const float* be3 = (const float*)d_in[13];
    const float* W4 = (const float*)d_in[14];
    const float* b4 = (const float*)d_in[15];
    const float* g4 = (const float*)d_in[16];
    const float* be4 = (const float*)d_in[17];
    const float* Wc = (const float*)d_in[18];
    const float* bc = (const float*)d_in[19];

    char* ws = (char*)d_ws;
    size_t off = 0;
    auto alloc = [&](size_t bytes) -> void* {
        void* p = ws + off;
        off += (bytes + 255) & ~(size_t)255;
        return p;
    };
    uint* ch = (uint*)alloc(65536 * 4);
    uint* bucketBase = (uint*)alloc(257 * 4);
    uint* pair = (uint*)alloc((size_t)N_EDGES * 4);
    int* rowptr = (int*)alloc((size_t)(N_NODES + 1) * 4);
    float* dinv = (float*)alloc((size_t)N_NODES * 4);
    int* colidx = (int*)alloc((size_t)N_EDGES * 4);
    float* rowsumP = (float*)alloc((size_t)N_NODES * 4);
    uint* xs = (uint*)alloc((size_t)N_NODES * 32 * 4);    // [N,64] bf16, dinv-prescaled + dinv@dim39
    ushort* Wfrag = (ushort*)alloc(32768);
    float* vB = (float*)alloc(128 * 4);
    float* sArr = (float*)alloc(128 * 4);
    float* uArr = (float*)alloc(128 * 4);
    float* Psum = (float*)alloc((size_t)128 * 2048 * 4);
    float* Psq = (float*)alloc((size_t)128 * 2048 * 4);
    ushort* P = (ushort*)alloc((size_t)N_NODES * 64 * 2);  // z3s -> z4s
    ushort* Q = (ushort*)alloc((size_t)N_NODES * 64 * 2);  // t1s -> t3
    ushort* R = (ushort*)alloc((size_t)N_NODES * 128 * 2); // t2 bf16; later t4 bf16 [N,32]
    if (off > ws_size) return;

    // ---- CSR build ----
    coarseA_kernel<<<NB_C, 256, 0, stream>>>(ei, ch);
    scanB_kernel<<<1, 256, 0, stream>>>(ch, bucketBase);
    scatterC_kernel<<<NB_C, 256, 0, stream>>>(ei, ch, pair);
    bucketD_kernel<<<NB_D, 256, 0, stream>>>(pair, bucketBase, rowptr, dinv, colidx);

    // ---- prep ----
    xscale_kernel<<<(N_NODES * 32 + 255) / 256, 256, 0, stream>>>(x, dinv, xs);
    foldpack_kernel<<<8, 256, 0, stream>>>(W1, nullptr, nullptr, Wfrag, nullptr, 39, 64, 64);

    // ---- Layer 1 (fused): a1 = Ahat x (+rowsumP) -> t1 = relu(a1@W1+b1); stats1; t1s ----
    fused_kernel<64, 0, 1><<<MG_GRID, 256, 0, stream>>>(
        (const ushort*)xs, rowptr, colidx, dinv, Wfrag, b1, nullptr, rowsumP,
        Q, Psum, Psq);
    reduce_bn_kernel<<<64, 256, 0, stream>>>(Psum, Psq, MG_GRID, g1, be1, sArr, uArr);
    foldpack_kernel<<<17, 256, 0, stream>>>(W2, sArr, uArr, Wfrag, vB, 64, 128, 64);

    // ---- Layer 2 (fused): a2 = Ahat t1s -> t2 = relu(a2@W2f + b2 + rowsumP*v2); stats2 ----
    fused_kernel<128, 1, 0><<<MG_GRID, 256, 0, stream>>>(
        Q, rowptr, colidx, dinv, Wfrag, b2, vB, rowsumP,
        R, Psum, Psq);
    reduce_bn_kernel<<<128, 256, 0, stream>>>(Psum, Psq, MG_GRID, g2, be2, sArr, uArr);
    foldpack_kernel<<<17, 256, 0, stream>>>(W3, sArr, uArr, Wfrag, vB, 128, 64, 128);

    // ---- Layer 3: z3s = bf16(dinv*(t2@W3f+v3)); t3 = relu(Ahat z3 + b3); stats3 ----
    mgemm_kernel<128, 64, 2><<<MG_GRID, 256, 0, stream>>>(
        R, Wfrag, vB, nullptr, nullptr, dinv, P, nullptr, nullptr);
    agg_kernel<64, 1, 0><<<AGG_GRID, 256, 0, stream>>>(
        P, rowptr, colidx, dinv, b3, Q, nullptr, Psum, Psq);
    reduce_bn_kernel<<<64, 256, 0, stream>>>(Psum, Psq, AGG_GRID, g3, be3, sArr, uArr);
    foldpack_kernel<<<5, 256, 0, stream>>>(W4, sArr, uArr, Wfrag, vB, 64, 32, 64);

    // ---- Layer 4: z4s = bf16(dinv*(t3@W4f+v4)); t4 = relu(Ahat z4 + b4) bf16; stats4 ----
    mgemm_kernel<64, 32, 2><<<MG_GRID, 256, 0, stream>>>(
        Q, Wfrag, vB, nullptr, nullptr, dinv, P, nullptr, nullptr);
    agg_kernel<32, 1, 0><<<AGG_GRID, 256, 0, stream>>>(
        P, rowptr, colidx, dinv, b4, R, nullptr, Psum, Psq);
    reduce_bn_kernel<<<32, 256, 0, stream>>>(Psum, Psq, AGG_GRID, g4, be4, sArr, uArr);

    // ---- final ----
    float* out_logits = (float*)d_out;
    float* out_h = (float*)d_out + (size_t)N_NODES * 5;
    final_kernel<<<(N_NODES + 255) / 256, 256, 0, stream>>>(R, sArr, uArr, Wc, bc,
                                                            out_logits, out_h);
}

// Round 11
// 410.808 us; speedup vs baseline: 1.1664x; 1.1664x over previous
//
#include <hip/hip_runtime.h>

typedef unsigned int uint;
typedef unsigned short ushort;
typedef __attribute__((ext_vector_type(8))) short bf16x8;
typedef __attribute__((ext_vector_type(4))) float f32x4;
typedef __attribute__((ext_vector_type(4))) uint uintx4;

#define N_NODES 100000
#define N_EDGES 1600000
#define NB_C 256
#define TILE_C ((N_EDGES + NB_C - 1) / NB_C)
#define NB_D ((N_NODES + 511) / 512)
#define MG_GRID ((N_NODES + 63) / 64)
#define AGG_GRID 2048
constexpr float BN_EPS = 1e-5f;

__device__ __forceinline__ float bflo(uint w) { return __uint_as_float(w << 16); }
__device__ __forceinline__ float bfhi(uint w) { return __uint_as_float(w & 0xffff0000u); }
__device__ __forceinline__ ushort f2bf(float x) {
    uint u = __float_as_uint(x);
    uint r = (u + 0x7fffu + ((u >> 16) & 1u)) >> 16;
    return (ushort)r;
}
__device__ __forceinline__ uint pack2(float a, float b) {
    return (uint)f2bf(a) | ((uint)f2bf(b) << 16);
}

// per-wave int64 detection: all waves read the same 64 odd words -> consistent
__device__ __forceinline__ bool detect_i64(const int* __restrict__ ep)
{
    int lane = threadIdx.x & 63;
    unsigned long long nz = __ballot(ep[2 * lane + 1] != 0);
    return nz == 0ULL;
}

// ---------------- CSR build: atomic-free bucket sort ----------------
__global__ __launch_bounds__(256) void coarseA_kernel(const int* __restrict__ ep,
                                                      uint* __restrict__ ch)
{
    __shared__ uint lh[256];
    int t = threadIdx.x, blk = blockIdx.x;
    lh[t] = 0;
    bool i64 = detect_i64(ep);
    __syncthreads();
    int start = blk * TILE_C;
    int end = start + TILE_C;
    if (end > N_EDGES) end = N_EDGES;
    for (int e = start + t; e < end; e += 256) {
        int d = i64 ? ep[2 * (N_EDGES + e)] : ep[N_EDGES + e];
        atomicAdd(&lh[d >> 9], 1u);
    }
    __syncthreads();
    ch[t * NB_C + blk] = lh[t];
}

__global__ void scanB_kernel(uint* __restrict__ ch, uint* __restrict__ bucketBase)
{
    __shared__ uint tot[256];
    int t = threadIdx.x;
    uint s = 0;
    for (int i = 0; i < NB_C; i++) s += ch[t * NB_C + i];
    tot[t] = s;
    __syncthreads();
    for (int off = 1; off < 256; off <<= 1) {
        uint add = (t >= off) ? tot[t - off] : 0u;
        __syncthreads();
        tot[t] += add;
        __syncthreads();
    }
    uint base = tot[t] - s;
    bucketBase[t] = base;
    if (t == 255) bucketBase[256] = base + s;
    uint run = base;
    for (int i = 0; i < NB_C; i++) {
        uint c = ch[t * NB_C + i];
        ch[t * NB_C + i] = run;
        run += c;
    }
}

// pair packing: low 17 bits = src, bits 17..25 = dst & 511
__global__ __launch_bounds__(256) void scatterC_kernel(const int* __restrict__ ep,
                                                       const uint* __restrict__ ch,
                                                       uint* __restrict__ pair)
{
    __shared__ uint loff[256];
    int t = threadIdx.x, blk = blockIdx.x;
    loff[t] = ch[t * NB_C + blk];
    bool i64 = detect_i64(ep);
    __syncthreads();
    int start = blk * TILE_C;
    int end = start + TILE_C;
    if (end > N_EDGES) end = N_EDGES;
    for (int e = start + t; e < end; e += 256) {
        int s, d;
        if (i64) { s = ep[2 * e]; d = ep[2 * (N_EDGES + e)]; }
        else     { s = ep[e];     d = ep[N_EDGES + e]; }
        uint pos = atomicAdd(&loff[d >> 9], 1u);
        pair[pos] = (uint)s | ((uint)(d & 511) << 17);
    }
}

__global__ __launch_bounds__(256) void bucketD_kernel(const uint* __restrict__ pair,
                                                      const uint* __restrict__ bucketBase,
                                                      int* __restrict__ rowptr,
                                                      float* __restrict__ dinv,
                                                      int* __restrict__ colidx)
{
    __shared__ uint cnt[512], offp[512], s2[256];
    int bin = blockIdx.x, t = threadIdx.x;
    cnt[t] = 0; cnt[t + 256] = 0;
    __syncthreads();
    uint lo = bucketBase[bin], hi = bucketBase[bin + 1];
    for (uint p = lo + t; p < hi; p += 256)
        atomicAdd(&cnt[(pair[p] >> 17) & 511], 1u);
    __syncthreads();
    uint a = cnt[2 * t], b = cnt[2 * t + 1];
    s2[t] = a + b;
    __syncthreads();
    for (int off = 1; off < 256; off <<= 1) {
        uint add = (t >= off) ? s2[t - off] : 0u;
        __syncthreads();
        s2[t] += add;
        __syncthreads();
    }
    uint excl = s2[t] - (a + b);
    offp[2 * t] = excl;
    offp[2 * t + 1] = excl + a;
    __syncthreads();
    for (int k = t; k < 512; k += 256) {
        int d = bin * 512 + k;
        if (d < N_NODES) {
            rowptr[d] = (int)(lo + offp[k]);
            dinv[d] = rsqrtf((float)(cnt[k] + 1));
        }
    }
    if (bin == 0 && t == 0) rowptr[N_NODES] = N_EDGES;
    __syncthreads();
    for (uint p = lo + t; p < hi; p += 256) {
        uint pr = pair[p];
        uint pos = lo + atomicAdd(&offp[(pr >> 17) & 511], 1u);
        colidx[pos] = (int)(pr & 0x1FFFFu);
    }
}

// ---------------- xs[i][c] = bf16(dinv[i]*x[i][c]); dim 39 = dinv[i]; pad 40..63 = 0 ----------------
__global__ __launch_bounds__(256) void xscale_kernel(const float* __restrict__ x,
                                                     const float* __restrict__ dinv,
                                                     uint* __restrict__ xs)
{
    int idx = blockIdx.x * 256 + threadIdx.x;
    if (idx >= N_NODES * 32) return;
    int i = idx >> 5;
    int u = idx & 31;
    int c0 = 2 * u, c1 = 2 * u + 1;
    float di = dinv[i];
    float v0 = (c0 < 39) ? x[i * 39 + c0] * di : 0.f;
    float v1 = (c1 < 39) ? x[i * 39 + c1] * di : ((c1 == 39) ? di : 0.f);
    xs[idx] = pack2(v0, v1);
}

// ---------------- fused BN-fold + fragment pack ----------------
__global__ void foldpack_kernel(const float* __restrict__ W, const float* __restrict__ s,
                                const float* __restrict__ u, ushort* __restrict__ Wfrag,
                                float* __restrict__ vB, int din, int dout, int K)
{
    int CT = dout >> 4, KT = K >> 5;
    int nf = KT * CT;
    int b = blockIdx.x;
    if (b < nf) {
        int kt = b / CT, ct = b - kt * CT;
        for (int q = threadIdx.x; q < 512; q += 256) {
            int j = q & 7, lane = q >> 3;
            int k = kt * 32 + (lane >> 4) * 8 + j;
            int c = ct * 16 + (lane & 15);
            float v = 0.f;
            if (k < din) {
                float sv = s ? s[k] : 1.f;
                v = sv * W[k * dout + c];
            }
            Wfrag[(size_t)b * 512 + q] = f2bf(v);
        }
    } else {
        int c = threadIdx.x;
        if (u && c < dout) {
            float acc = 0.f;
            for (int k = 0; k < din; k++) acc += u[k] * W[k * dout + c];
            vB[c] = acc;
        }
    }
}

// ---------------- aggregation: wide dwordx4 gathers, round-6 predicated loop ----------------
// table row-major [N][D] bf16. lane = seg(D/8 x 16B) x slot(edges).
// MODE 0: out bf16 = dinv_i * acc          (+ rowsumP from dim 39 when WRSUM)
// MODE 1: out bf16 = relu(dinv_i*acc + bias), stats partials
template <int D, int MODE, int WRSUM>
__global__ __launch_bounds__(256) void agg_kernel(
    const ushort* __restrict__ table, const int* __restrict__ rowptr,
    const int* __restrict__ colidx, const float* __restrict__ dinv,
    const float* __restrict__ bias,
    ushort* __restrict__ outB, float* __restrict__ rowsumP,
    float* __restrict__ Psum, float* __restrict__ Psq)
{
    constexpr int LPE = D / 8;   // lanes per edge (16B chunks per row)
    constexpr int S = 64 / LPE;  // edge slots per wave
    int tid = threadIdx.x;
    int lane = tid & 63, wid = tid >> 6;
    int seg = lane & (LPE - 1);
    int slot = lane / LPE;
    const ushort* segbase = table + seg * 8;

    float bv[8];
    if constexpr (MODE == 1) {
        float4 b0 = *(const float4*)&bias[seg * 8];
        float4 b1 = *(const float4*)&bias[seg * 8 + 4];
        bv[0] = b0.x; bv[1] = b0.y; bv[2] = b0.z; bv[3] = b0.w;
        bv[4] = b1.x; bv[5] = b1.y; bv[6] = b1.z; bv[7] = b1.w;
    }
    float lsum[8] = {}, lsq[8] = {};

    for (int i = blockIdx.x * 4 + wid; i < N_NODES; i += gridDim.x * 4) {
        int iu = __builtin_amdgcn_readfirstlane(i);
        int s0 = rowptr[iu], e0 = rowptr[iu + 1];
        float acc[8] = {};
        if (slot == 0) {
            const uintx4 w = *(const uintx4*)(segbase + (size_t)iu * D);
            acc[0] = bflo(w.x); acc[1] = bfhi(w.x);
            acc[2] = bflo(w.y); acc[3] = bfhi(w.y);
            acc[4] = bflo(w.z); acc[5] = bfhi(w.z);
            acc[6] = bflo(w.w); acc[7] = bfhi(w.w);
        }
        for (int eb = s0; eb < e0; eb += S) {
            int e = eb + slot;
            if (e < e0) {
                int j = colidx[e];
                const uintx4 w = *(const uintx4*)(segbase + (size_t)j * D);
                acc[0] += bflo(w.x); acc[1] += bfhi(w.x);
                acc[2] += bflo(w.y); acc[3] += bfhi(w.y);
                acc[4] += bflo(w.z); acc[5] += bfhi(w.z);
                acc[6] += bflo(w.w); acc[7] += bfhi(w.w);
            }
        }
#pragma unroll
        for (int m = LPE; m < 64; m <<= 1) {
#pragma unroll
            for (int v = 0; v < 8; v++) acc[v] += __shfl_xor(acc[v], m);
        }
        if (slot == 0) {
            float di = dinv[iu];
            if constexpr (MODE == 0) {
                uintx4 pk;
                pk.x = pack2(di * acc[0], di * acc[1]);
                pk.y = pack2(di * acc[2], di * acc[3]);
                pk.z = pack2(di * acc[4], di * acc[5]);
                pk.w = pack2(di * acc[6], di * acc[7]);
                *(uintx4*)(outB + (size_t)iu * D + seg * 8) = pk;
                if constexpr (WRSUM) {
                    if (seg == 4) rowsumP[iu] = di * acc[7];  // dim 39 carries dinv
                }
            } else {
                float t[8];
#pragma unroll
                for (int v = 0; v < 8; v++) {
                    t[v] = fmaxf(fmaf(di, acc[v], bv[v]), 0.f);
                    lsum[v] += t[v];
                    lsq[v] += t[v] * t[v];
                }
                uintx4 pk;
                pk.x = pack2(t[0], t[1]); pk.y = pack2(t[2], t[3]);
                pk.z = pack2(t[4], t[5]); pk.w = pack2(t[6], t[7]);
                *(uintx4*)(outB + (size_t)iu * D + seg * 8) = pk;
            }
        }
    }

    if constexpr (MODE == 1) {
        __shared__ float ssum[D], ssq[D];
        for (int c = tid; c < D; c += 256) { ssum[c] = 0.f; ssq[c] = 0.f; }
        __syncthreads();
        if (slot == 0) {
#pragma unroll
            for (int v = 0; v < 8; v++) {
                atomicAdd(&ssum[seg * 8 + v], lsum[v]);
                atomicAdd(&ssq[seg * 8 + v], lsq[v]);
            }
        }
        __syncthreads();
        for (int c = tid; c < D; c += 256) {
            Psum[(size_t)c * gridDim.x + blockIdx.x] = ssum[c];
            Psq[(size_t)c * gridDim.x + blockIdx.x] = ssq[c];
        }
    }
}

// ---------------- MFMA GEMM (row-major A and out) ----------------
// MODE 0: t=relu(acc+bias); stats; out bf16 = dinv[r]*t
// MODE 1: t=relu(acc+bias+rowsumP[r]*bias2); stats; out bf16 = t
// MODE 2: z=acc+bias; out bf16 = dinv[r]*z
template <int K, int DOUT, int MODE>
__global__ __launch_bounds__(256) void mgemm_kernel(
    const ushort* __restrict__ A, const ushort* __restrict__ Wfrag,
    const float* __restrict__ bias, const float* __restrict__ bias2,
    const float* __restrict__ rowsumP, const float* __restrict__ dinv,
    ushort* __restrict__ outB, float* __restrict__ Psum, float* __restrict__ Psq)
{
    constexpr int KT = K / 32, CT = DOUT / 16;
    int tid = threadIdx.x;
    int lane = tid & 63, wid = tid >> 6;
    int r0 = blockIdx.x * 64 + wid * 16;
    int arow = r0 + (lane & 15);
    if (arow >= N_NODES) arow = N_NODES - 1;
    const ushort* aptr = A + (size_t)arow * K + (lane >> 4) * 8;

    f32x4 acc[CT];
#pragma unroll
    for (int ct = 0; ct < CT; ct++) acc[ct] = (f32x4){0.f, 0.f, 0.f, 0.f};

#pragma unroll
    for (int kt = 0; kt < KT; kt++) {
        bf16x8 af = *(const bf16x8*)(aptr + kt * 32);
        const ushort* wp = Wfrag + ((size_t)(kt * CT) * 64 + lane) * 8;
#pragma unroll
        for (int ct = 0; ct < CT; ct++) {
            bf16x8 bfr = *(const bf16x8*)(wp + (size_t)ct * 64 * 8);
            acc[ct] = __builtin_amdgcn_mfma_f32_16x16x32_bf16(af, bfr, acc[ct], 0, 0, 0);
        }
    }

    int colbase = lane & 15;
    int rgrp = lane >> 4;
    int rows[4]; bool rok[4];
    float rP[4], rD[4];
#pragma unroll
    for (int i = 0; i < 4; i++) {
        int r = r0 + rgrp * 4 + i;
        rows[i] = r;
        rok[i] = (r < N_NODES);
        int rc = rok[i] ? r : 0;
        if constexpr (MODE == 1) rP[i] = rowsumP[rc];
        else rD[i] = dinv[rc];
    }

    __shared__ float ssum[DOUT], ssq[DOUT];
    if constexpr (MODE <= 1) {
        for (int c = tid; c < DOUT; c += 256) { ssum[c] = 0.f; ssq[c] = 0.f; }
        __syncthreads();
    }

#pragma unroll
    for (int ct = 0; ct < CT; ct++) {
        int col = ct * 16 + colbase;
        float b = bias[col];
        float b2 = 0.f;
        if constexpr (MODE == 1) b2 = bias2[col];
        float cs = 0.f, cq = 0.f;
#pragma unroll
        for (int i = 0; i < 4; i++) {
            float v = acc[ct][i] + b;
            if constexpr (MODE == 1) v = fmaf(rP[i], b2, v);
            if constexpr (MODE <= 1) v = fmaxf(v, 0.f);
            float w = (MODE == 1) ? v : rD[i] * v;
            if (rok[i]) {
                outB[(size_t)rows[i] * DOUT + col] = f2bf(w);
                if constexpr (MODE <= 1) { cs += v; cq += v * v; }
            }
        }
        if constexpr (MODE <= 1) {
            cs += __shfl_xor(cs, 16); cs += __shfl_xor(cs, 32);
            cq += __shfl_xor(cq, 16); cq += __shfl_xor(cq, 32);
            if (rgrp == 0) {
                atomicAdd(&ssum[col], cs);
                atomicAdd(&ssq[col], cq);
            }
        }
    }
    if constexpr (MODE <= 1) {
        __syncthreads();
        for (int c = tid; c < DOUT; c += 256) {
            Psum[(size_t)c * gridDim.x + blockIdx.x] = ssum[c];
            Psq[(size_t)c * gridDim.x + blockIdx.x] = ssq[c];
        }
    }
}

// ---------------- BN stat reduce -> scale/shift ----------------
__global__ __launch_bounds__(256) void reduce_bn_kernel(
    const float* __restrict__ Psum, const float* __restrict__ Psq, int nb,
    const float* __restrict__ g, const float* __restrict__ be,
    float* __restrict__ sOut, float* __restrict__ uOut)
{
    int c = blockIdx.x, t = threadIdx.x;
    float s = 0.f, q = 0.f;
    for (int i = t; i < nb; i += 256) {
        s += Psum[(size_t)c * nb + i];
        q += Psq[(size_t)c * nb + i];
    }
    __shared__ float rs[256], rq[256];
    rs[t] = s; rq[t] = q;
    __syncthreads();
    for (int off = 128; off > 0; off >>= 1) {
        if (t < off) { rs[t] += rs[t + off]; rq[t] += rq[t + off]; }
        __syncthreads();
    }
    if (t == 0) {
        float mu = rs[0] * (1.0f / N_NODES);
        float var = rq[0] * (1.0f / N_NODES) - mu * mu;
        float sv = g[c] * rsqrtf(var + BN_EPS);
        sOut[c] = sv;
        uOut[c] = be[c] - mu * sv;
    }
}

// ---------------- final: h4 = s4*t4+u4 (t4 [N,32] bf16), logits = h4@Wc+bc ----------------
__global__ __launch_bounds__(256) void final_kernel(
    const ushort* __restrict__ t4, const float* __restrict__ sArr,
    const float* __restrict__ uArr, const float* __restrict__ Wc,
    const float* __restrict__ bc, float* __restrict__ out_logits,
    float* __restrict__ out_h)
{
    __shared__ float sc[32], sh2[32], Wcs[160], bcs[5];
    int t = threadIdx.x;
    if (t < 32) { sc[t] = sArr[t]; sh2[t] = uArr[t]; }
    if (t < 160) Wcs[t] = Wc[t];
    if (t < 5) bcs[t] = bc[t];
    __syncthreads();
    int i = blockIdx.x * blockDim.x + t;
    if (i >= N_NODES) return;
    float hv[32];
    const uint* tp = (const uint*)(t4 + (size_t)i * 32);
#pragma unroll
    for (int q = 0; q < 4; q++) {
        uintx4 w = *(const uintx4*)(tp + q * 4);
        int f0 = q * 8;
        hv[f0 + 0] = fmaf(sc[f0 + 0], bflo(w.x), sh2[f0 + 0]);
        hv[f0 + 1] = fmaf(sc[f0 + 1], bfhi(w.x), sh2[f0 + 1]);
        hv[f0 + 2] = fmaf(sc[f0 + 2], bflo(w.y), sh2[f0 + 2]);
        hv[f0 + 3] = fmaf(sc[f0 + 3], bfhi(w.y), sh2[f0 + 3]);
        hv[f0 + 4] = fmaf(sc[f0 + 4], bflo(w.z), sh2[f0 + 4]);
        hv[f0 + 5] = fmaf(sc[f0 + 5], bfhi(w.z), sh2[f0 + 5]);
        hv[f0 + 6] = fmaf(sc[f0 + 6], bflo(w.w), sh2[f0 + 6]);
        hv[f0 + 7] = fmaf(sc[f0 + 7], bfhi(w.w), sh2[f0 + 7]);
    }
#pragma unroll
    for (int f0 = 0; f0 < 32; f0 += 4) {
        float4 v = {hv[f0], hv[f0 + 1], hv[f0 + 2], hv[f0 + 3]};
        *(float4*)&out_h[(size_t)i * 32 + f0] = v;
    }
    float o[5];
#pragma unroll
    for (int c = 0; c < 5; c++) o[c] = bcs[c];
#pragma unroll
    for (int f = 0; f < 32; f++) {
        float hvf = hv[f];
#pragma unroll
        for (int c = 0; c < 5; c++) o[c] = fmaf(hvf, Wcs[f * 5 + c], o[c]);
    }
#pragma unroll
    for (int c = 0; c < 5; c++) out_logits[(size_t)i * 5 + c] = o[c];
}

extern "C" void kernel_launch(void* const* d_in, const int* in_sizes, int n_in,
                              void* d_out, int out_size, void* d_ws, size_t ws_size,
                              hipStream_t stream)
{
    const float* x = (const float*)d_in[0];
    const int* ei = (const int*)d_in[1];
    const float* W1 = (const float*)d_in[2];
    const float* b1 = (const float*)d_in[3];
    const float* g1 = (const float*)d_in[4];
    const float* be1 = (const float*)d_in[5];
    const float* W2 = (const float*)d_in[6];
    const float* b2 = (const float*)d_in[7];
    const float* g2 = (const float*)d_in[8];
    const float* be2 = (const float*)d_in[9];
    const float* W3 = (const float*)d_in[10];
    const float* b3 = (const float*)d_in[11];
    const float* g3 = (const float*)d_in[12];
    const float* be3 = (const float*)d_in[13];
    const float* W4 = (const float*)d_in[14];
    const float* b4 = (const float*)d_in[15];
    const float* g4 = (const float*)d_in[16];
    const float* be4 = (const float*)d_in[17];
    const float* Wc = (const float*)d_in[18];
    const float* bc = (const float*)d_in[19];

    char* ws = (char*)d_ws;
    size_t off = 0;
    auto alloc = [&](size_t bytes) -> void* {
        void* p = ws + off;
        off += (bytes + 255) & ~(size_t)255;
        return p;
    };
    uint* ch = (uint*)alloc(65536 * 4);
    uint* bucketBase = (uint*)alloc(257 * 4);
    uint* pair = (uint*)alloc((size_t)N_EDGES * 4);
    int* rowptr = (int*)alloc((size_t)(N_NODES + 1) * 4);
    float* dinv = (float*)alloc((size_t)N_NODES * 4);
    int* colidx = (int*)alloc((size_t)N_EDGES * 4);
    float* rowsumP = (float*)alloc((size_t)N_NODES * 4);
    uint* xs = (uint*)alloc((size_t)N_NODES * 32 * 4);    // [N,64] bf16, dinv-prescaled + dinv@dim39
    ushort* Wfrag = (ushort*)alloc(32768);
    float* vB = (float*)alloc(128 * 4);
    float* sArr = (float*)alloc(128 * 4);
    float* uArr = (float*)alloc(128 * 4);
    float* Psum = (float*)alloc((size_t)128 * 2048 * 4);
    float* Psq = (float*)alloc((size_t)128 * 2048 * 4);
    ushort* P = (ushort*)alloc((size_t)N_NODES * 64 * 2);  // a1 -> a2 -> z3s -> z4s
    ushort* Q = (ushort*)alloc((size_t)N_NODES * 64 * 2);  // t1s -> t3
    ushort* R = (ushort*)alloc((size_t)N_NODES * 128 * 2); // t2 bf16; later t4 bf16 [N,32]
    if (off > ws_size) return;

    // ---- CSR build ----
    coarseA_kernel<<<NB_C, 256, 0, stream>>>(ei, ch);
    scanB_kernel<<<1, 256, 0, stream>>>(ch, bucketBase);
    scatterC_kernel<<<NB_C, 256, 0, stream>>>(ei, ch, pair);
    bucketD_kernel<<<NB_D, 256, 0, stream>>>(pair, bucketBase, rowptr, dinv, colidx);

    // ---- prep ----
    xscale_kernel<<<(N_NODES * 32 + 255) / 256, 256, 0, stream>>>(x, dinv, xs);
    foldpack_kernel<<<8, 256, 0, stream>>>(W1, nullptr, nullptr, Wfrag, nullptr, 39, 64, 64);

    // ---- Layer 1: a1 = Ahat x (+ rowsumP); t1 = relu(a1@W1+b1); stats1; t1s ----
    agg_kernel<64, 0, 1><<<AGG_GRID, 256, 0, stream>>>(
        (const ushort*)xs, rowptr, colidx, dinv, nullptr, P, rowsumP, nullptr, nullptr);
    mgemm_kernel<64, 64, 0><<<MG_GRID, 256, 0, stream>>>(
        P, Wfrag, b1, nullptr, nullptr, dinv, Q, Psum, Psq);
    reduce_bn_kernel<<<64, 256, 0, stream>>>(Psum, Psq, MG_GRID, g1, be1, sArr, uArr);
    foldpack_kernel<<<17, 256, 0, stream>>>(W2, sArr, uArr, Wfrag, vB, 64, 128, 64);

    // ---- Layer 2: a2 = Ahat t1s ; t2 = relu(a2@W2f + b2 + rowsumP*v2); stats2 ----
    agg_kernel<64, 0, 0><<<AGG_GRID, 256, 0, stream>>>(
        Q, rowptr, colidx, dinv, nullptr, P, nullptr, nullptr, nullptr);
    mgemm_kernel<64, 128, 1><<<MG_GRID, 256, 0, stream>>>(
        P, Wfrag, b2, vB, rowsumP, nullptr, R, Psum, Psq);
    reduce_bn_kernel<<<128, 256, 0, stream>>>(Psum, Psq, MG_GRID, g2, be2, sArr, uArr);
    foldpack_kernel<<<17, 256, 0, stream>>>(W3, sArr, uArr, Wfrag, vB, 128, 64, 128);

    // ---- Layer 3: z3s = bf16(dinv*(t2@W3f+v3)); t3 = relu(Ahat z3 + b3); stats3 ----
    mgemm_kernel<128, 64, 2><<<MG_GRID, 256, 0, stream>>>(
        R, Wfrag, vB, nullptr, nullptr, dinv, P, nullptr, nullptr);
    agg_kernel<64, 1, 0><<<AGG_GRID, 256, 0, stream>>>(
        P, rowptr, colidx, dinv, b3, Q, nullptr, Psum, Psq);
    reduce_bn_kernel<<<64, 256, 0, stream>>>(Psum, Psq, AGG_GRID, g3, be3, sArr, uArr);
    foldpack_kernel<<<5, 256, 0, stream>>>(W4, sArr, uArr, Wfrag, vB, 64, 32, 64);

    // ---- Layer 4: z4s = bf16(dinv*(t3@W4f+v4)); t4 = relu(Ahat z4 + b4) bf16; stats4 ----
    mgemm_kernel<64, 32, 2><<<MG_GRID, 256, 0, stream>>>(
        Q, Wfrag, vB, nullptr, nullptr, dinv, P, nullptr, nullptr);
    agg_kernel<32, 1, 0><<<AGG_GRID, 256, 0, stream>>>(
        P, rowptr, colidx, dinv, b4, R, nullptr, Psum, Psq);
    reduce_bn_kernel<<<32, 256, 0, stream>>>(Psum, Psq, AGG_GRID, g4, be4, sArr, uArr);

    // ---- final ----
    float* out_logits = (float*)d_out;
    float* out_h = (float*)d_out + (size_t)N_NODES * 5;
    final_kernel<<<(N_NODES + 255) / 256, 256, 0, stream>>>(R, sArr, uArr, Wc, bc,
                                                            out_logits, out_h);
}